// Round 1
// baseline (44534.866 us; speedup 1.0000x reference)
//
#include <hip/hip_runtime.h>
#include <math.h>

#define B_ 64
#define T_ 256
#define C_ 2048
#define WE_ 256
#define H_ 1024
#define G3_ 3072

__device__ __forceinline__ float sigmoidf_(float x) { return 1.f / (1.f + expf(-x)); }

// Normalize mask to float 0/1 regardless of whether the harness passed bool as
// int32 or as raw bytes. Safe: only reads bytes valid under both layouts
// unless int32-layout is detected (in which case the buffer really is 4x).
__global__ void k_maskprep(const unsigned char* __restrict__ m, float* __restrict__ mf) {
    int idx = blockIdx.x * 256 + threadIdx.x;  // 0..16383
    bool bytemode = (m[1] != 0);               // mask[0][1] is always true (words_num>=128)
    unsigned char v = bytemode ? m[idx] : m[(size_t)idx * 4];
    mf[idx] = v ? 1.f : 0.f;
}

__global__ void k_hinit(const float* __restrict__ enc, float* __restrict__ h) {
    int idx = blockIdx.x * 256 + threadIdx.x;  // 0..65535
    int b = idx >> 10, k = idx & (H_ - 1);
    h[idx] = enc[((size_t)b * T_ + (T_ - 1)) * H_ + k];
}

// gi[b][j] = b_ih[j] + sum_e E[ids[b]][e]*W_ih[j][e]
// gh[b][j] = b_hh[j] + sum_k h[b][k]   *W_hh[j][k]
// Tile: all 64 b x 32 j per block; grid = 3072/32 = 96 blocks.
__global__ __launch_bounds__(256) void k_gates(
    const float* __restrict__ E, const int* __restrict__ targets,
    const float* __restrict__ Wih, const float* __restrict__ Whh,
    const float* __restrict__ bih, const float* __restrict__ bhh,
    const float* __restrict__ h, float* __restrict__ gi, float* __restrict__ gh,
    int t)
{
    __shared__ float As[32 * 68];  // [kk][b], padded row 68 (16B-aligned rows, bank-spread)
    __shared__ float Ws[32 * 33];  // [kk][j], padded row 33
    __shared__ int ids[B_];
    const int tid = threadIdx.x;
    const int j0 = blockIdx.x * 32;
    const int tx = tid & 31;   // j within tile
    const int ty = tid >> 5;   // 8 groups -> 8 b's each
    float acc_i[8], acc_h[8];
#pragma unroll
    for (int i = 0; i < 8; ++i) { acc_i[i] = 0.f; acc_h[i] = 0.f; }
    if (tid < B_) ids[tid] = (t == 0) ? 0 : targets[tid * T_ + t - 1];
    __syncthreads();

    // ---- x part: K = 256 (8 chunks of 32) ----
    for (int c = 0; c < 8; ++c) {
        int k0 = c * 32;
#pragma unroll
        for (int r = 0; r < 2; ++r) {
            int lin = tid + 256 * r;          // 0..511 float4 slots (64 b x 8 k4)
            int k4 = lin & 7, b = lin >> 3;
            float4 v = *(const float4*)&E[(size_t)ids[b] * WE_ + k0 + k4 * 4];
            int kk = k4 * 4;
            As[(kk + 0) * 68 + b] = v.x; As[(kk + 1) * 68 + b] = v.y;
            As[(kk + 2) * 68 + b] = v.z; As[(kk + 3) * 68 + b] = v.w;
        }
        {
            int k4 = tid & 7, jj = tid >> 3;  // 32 j x 8 k4
            float4 v = *(const float4*)&Wih[(size_t)(j0 + jj) * WE_ + k0 + k4 * 4];
            int kk = k4 * 4;
            Ws[(kk + 0) * 33 + jj] = v.x; Ws[(kk + 1) * 33 + jj] = v.y;
            Ws[(kk + 2) * 33 + jj] = v.z; Ws[(kk + 3) * 33 + jj] = v.w;
        }
        __syncthreads();
#pragma unroll
        for (int kk = 0; kk < 32; ++kk) {
            float w = Ws[kk * 33 + tx];
#pragma unroll
            for (int i = 0; i < 8; ++i) acc_i[i] += As[kk * 68 + ty * 8 + i] * w;
        }
        __syncthreads();
    }

    // ---- h part: K = 1024 (32 chunks of 32) ----
    for (int c = 0; c < 32; ++c) {
        int k0 = c * 32;
#pragma unroll
        for (int r = 0; r < 2; ++r) {
            int lin = tid + 256 * r;
            int k4 = lin & 7, b = lin >> 3;
            float4 v = *(const float4*)&h[(size_t)b * H_ + k0 + k4 * 4];
            int kk = k4 * 4;
            As[(kk + 0) * 68 + b] = v.x; As[(kk + 1) * 68 + b] = v.y;
            As[(kk + 2) * 68 + b] = v.z; As[(kk + 3) * 68 + b] = v.w;
        }
        {
            int k4 = tid & 7, jj = tid >> 3;
            float4 v = *(const float4*)&Whh[(size_t)(j0 + jj) * H_ + k0 + k4 * 4];
            int kk = k4 * 4;
            Ws[(kk + 0) * 33 + jj] = v.x; Ws[(kk + 1) * 33 + jj] = v.y;
            Ws[(kk + 2) * 33 + jj] = v.z; Ws[(kk + 3) * 33 + jj] = v.w;
        }
        __syncthreads();
#pragma unroll
        for (int kk = 0; kk < 32; ++kk) {
            float w = Ws[kk * 33 + tx];
#pragma unroll
            for (int i = 0; i < 8; ++i) acc_h[i] += As[kk * 68 + ty * 8 + i] * w;
        }
        __syncthreads();
    }

    float vi = bih[j0 + tx], vh = bhh[j0 + tx];
#pragma unroll
    for (int i = 0; i < 8; ++i) {
        int b = ty * 8 + i;
        gi[(size_t)b * G3_ + j0 + tx] = acc_i[i] + vi;
        gh[(size_t)b * G3_ + j0 + tx] = acc_h[i] + vh;
    }
}

// In-place GRU gate update: h <- (1-z)*n + z*h
__global__ __launch_bounds__(256) void k_gru(
    const float* __restrict__ gi, const float* __restrict__ gh, float* __restrict__ h)
{
    int idx = blockIdx.x * 256 + threadIdx.x;  // 0..65535
    int b = idx >> 10, k = idx & (H_ - 1);
    size_t o = (size_t)b * G3_ + k;
    float ir = gi[o], iz = gi[o + H_], in = gi[o + 2 * H_];
    float hr = gh[o], hz = gh[o + H_], hn = gh[o + 2 * H_];
    float r = sigmoidf_(ir + hr);
    float z = sigmoidf_(iz + hz);
    float n = tanhf(in + r * hn);
    h[idx] = (1.f - z) * n + z * h[idx];
}

// e_raw[b][t'] = dot(h[b], enc[b][t'])  — grid (4 t-chunks, 64 b), 4 lanes/dot
__global__ __launch_bounds__(256) void k_scores(
    const float* __restrict__ h, const float* __restrict__ enc, float* __restrict__ e_raw)
{
    __shared__ float hs[H_];
    const int b = blockIdx.y;
    const int tc = blockIdx.x;
    const int tid = threadIdx.x;
#pragma unroll
    for (int r = 0; r < 4; ++r) hs[tid + 256 * r] = h[(size_t)b * H_ + tid + 256 * r];
    __syncthreads();
    const int tl = tid >> 2, part = tid & 3;
    const int tt = tc * 64 + tl;
    const float4* row = (const float4*)(enc + ((size_t)b * T_ + tt) * H_);
    const float4* hv = (const float4*)hs;
    float acc = 0.f;
#pragma unroll 8
    for (int i = 0; i < 64; ++i) {
        float4 a = row[part * 64 + i];
        float4 x = hv[part * 64 + i];
        acc += a.x * x.x + a.y * x.y + a.z * x.z + a.w * x.w;
    }
    acc += __shfl_xor(acc, 1);
    acc += __shfl_xor(acc, 2);
    if (part == 0) e_raw[(size_t)b * T_ + tt] = acc;
}

// Fused masked softmax (recomputed per block, cheap) + context slice.
// grid (4 k-quarters, 64 b); c[b][k] = sum_t alpha[b][t] * enc[b][t][k]
__global__ __launch_bounds__(256) void k_ctx(
    const float* __restrict__ e_raw, const float* __restrict__ maskf,
    const float* __restrict__ enc, float* __restrict__ cvec)
{
    __shared__ float al[T_];
    __shared__ float red[256];
    const int b = blockIdx.y, q = blockIdx.x, tid = threadIdx.x;
    float e = (maskf[(size_t)b * T_ + tid] > 0.5f) ? e_raw[(size_t)b * T_ + tid] : -INFINITY;
    red[tid] = e; __syncthreads();
    for (int s = 128; s > 0; s >>= 1) { if (tid < s) red[tid] = fmaxf(red[tid], red[tid + s]); __syncthreads(); }
    float mx = red[0]; __syncthreads();
    float p = expf(e - mx);
    red[tid] = p; __syncthreads();
    for (int s = 128; s > 0; s >>= 1) { if (tid < s) red[tid] += red[tid + s]; __syncthreads(); }
    float denom = red[0];
    al[tid] = p / denom;
    __syncthreads();
    const int k = q * 256 + tid;
    float acc = 0.f;
#pragma unroll 8
    for (int tt2 = 0; tt2 < T_; ++tt2) {
        acc += al[tt2] * enc[((size_t)b * T_ + tt2) * H_ + k];
    }
    cvec[(size_t)b * H_ + k] = acc;
}

// out[b][t][j] = b_out[j] + sum_{k<2048} hc[b][k] * W_out[j][k], hc = [h ; c]
// grid = 2048/32 = 64 blocks.
__global__ __launch_bounds__(256) void k_logits(
    const float* __restrict__ h, const float* __restrict__ cvec,
    const float* __restrict__ Wout, const float* __restrict__ bout,
    float* __restrict__ out, int t)
{
    __shared__ float As[32 * 68];
    __shared__ float Ws[32 * 33];
    const int tid = threadIdx.x;
    const int j0 = blockIdx.x * 32;
    const int tx = tid & 31;
    const int ty = tid >> 5;
    float acc[8];
#pragma unroll
    for (int i = 0; i < 8; ++i) acc[i] = 0.f;

    for (int c = 0; c < 64; ++c) {
        int k0 = c * 32;
        const float* Ap = (k0 < H_) ? (h + k0) : (cvec + (k0 - H_));
#pragma unroll
        for (int r = 0; r < 2; ++r) {
            int lin = tid + 256 * r;
            int k4 = lin & 7, b = lin >> 3;
            float4 v = *(const float4*)&Ap[(size_t)b * H_ + k4 * 4];
            int kk = k4 * 4;
            As[(kk + 0) * 68 + b] = v.x; As[(kk + 1) * 68 + b] = v.y;
            As[(kk + 2) * 68 + b] = v.z; As[(kk + 3) * 68 + b] = v.w;
        }
        {
            int k4 = tid & 7, jj = tid >> 3;
            float4 v = *(const float4*)&Wout[(size_t)(j0 + jj) * (2 * H_) + k0 + k4 * 4];
            int kk = k4 * 4;
            Ws[(kk + 0) * 33 + jj] = v.x; Ws[(kk + 1) * 33 + jj] = v.y;
            Ws[(kk + 2) * 33 + jj] = v.z; Ws[(kk + 3) * 33 + jj] = v.w;
        }
        __syncthreads();
#pragma unroll
        for (int kk = 0; kk < 32; ++kk) {
            float w = Ws[kk * 33 + tx];
#pragma unroll
            for (int i = 0; i < 8; ++i) acc[i] += As[kk * 68 + ty * 8 + i] * w;
        }
        __syncthreads();
    }
    float bo = bout[j0 + tx];
#pragma unroll
    for (int i = 0; i < 8; ++i) {
        int b = ty * 8 + i;
        out[((size_t)b * T_ + t) * C_ + j0 + tx] = acc[i] + bo;
    }
}

extern "C" void kernel_launch(void* const* d_in, const int* in_sizes, int n_in,
                              void* d_out, int out_size, void* d_ws, size_t ws_size,
                              hipStream_t stream)
{
    const float* enc     = (const float*)d_in[0];
    const unsigned char* mask = (const unsigned char*)d_in[1];
    const int*   targets = (const int*)d_in[2];
    const float* E       = (const float*)d_in[3];
    const float* Wih     = (const float*)d_in[4];
    const float* Whh     = (const float*)d_in[5];
    const float* bih     = (const float*)d_in[6];
    const float* bhh     = (const float*)d_in[7];
    const float* Wout    = (const float*)d_in[8];
    const float* bout    = (const float*)d_in[9];
    float* out = (float*)d_out;

    float* ws    = (float*)d_ws;
    float* h     = ws;               // 65536
    float* gi    = h + 65536;        // 196608
    float* gh    = gi + 196608;      // 196608
    float* e_raw = gh + 196608;      // 16384
    float* maskf = e_raw + 16384;    // 16384
    float* cvec  = maskf + 16384;    // 65536

    k_maskprep<<<64, 256, 0, stream>>>(mask, maskf);
    k_hinit<<<256, 256, 0, stream>>>(enc, h);

    for (int t = 0; t < T_; ++t) {
        k_gates<<<96, 256, 0, stream>>>(E, targets, Wih, Whh, bih, bhh, h, gi, gh, t);
        k_gru<<<256, 256, 0, stream>>>(gi, gh, h);
        k_scores<<<dim3(4, 64), 256, 0, stream>>>(h, enc, e_raw);
        k_ctx<<<dim3(4, 64), 256, 0, stream>>>(e_raw, maskf, enc, cvec);
        k_logits<<<64, 256, 0, stream>>>(h, cvec, Wout, bout, out, t);
    }
}

// Round 2
// 14948.291 us; speedup vs baseline: 2.9793x; 2.9793x over previous
//
#include <hip/hip_runtime.h>
#include <hip/hip_bf16.h>
#include <math.h>

#define B_ 64
#define T_ 256
#define C_ 2048
#define WE_ 256
#define H_ 1024
#define G3_ 3072

typedef __attribute__((ext_vector_type(8))) short short8;
typedef __attribute__((ext_vector_type(4))) float f32x4;

__device__ __forceinline__ float sigmoidf_(float x) { return 1.f / (1.f + expf(-x)); }

// Normalize mask to float 0/1 regardless of bool-as-bytes vs bool-as-int32.
__global__ void k_maskprep(const unsigned char* __restrict__ m, float* __restrict__ mf) {
    int idx = blockIdx.x * 256 + threadIdx.x;  // 0..16383
    bool bytemode = (m[1] != 0);               // mask[0][1] always true (words_num>=128)
    unsigned char v = bytemode ? m[idx] : m[(size_t)idx * 4];
    mf[idx] = v ? 1.f : 0.f;
}

__global__ void k_hinit(const float* __restrict__ enc, float* __restrict__ h) {
    int idx = blockIdx.x * 256 + threadIdx.x;  // 0..65535
    int b = idx >> 10, k = idx & (H_ - 1);
    h[idx] = enc[((size_t)b * T_ + (T_ - 1)) * H_ + k];
}

// Convert W_out (2048x2048 fp32) to bf16 once.
__global__ void k_wprep(const float* __restrict__ Wout, __hip_bfloat16* __restrict__ Wb) {
    int i4 = blockIdx.x * 256 + threadIdx.x;   // 0..(4M/4 - 1)
    float4 v = *(const float4*)&Wout[(size_t)i4 * 4];
    __attribute__((aligned(8))) __hip_bfloat16 tmp[4] = {
        __float2bfloat16(v.x), __float2bfloat16(v.y),
        __float2bfloat16(v.z), __float2bfloat16(v.w)};
    *(uint2*)&Wb[(size_t)i4 * 4] = *(const uint2*)tmp;
}

// Split-K gates GEMM. grid (96, 2):
//   z=0: gi[b][j] (K=256 E-part, +bih) and gh0[b][j] = Whh K-chunks 0..11 (+bhh)
//   z=1: gh1[b][j] = Whh K-chunks 12..31
// Thread tile 4b x 2j (b128 A reads, b64 W reads): ~3 B/FMA LDS traffic.
__global__ __launch_bounds__(256) void k_gates(
    const float* __restrict__ E, const int* __restrict__ targets,
    const float* __restrict__ Wih, const float* __restrict__ Whh,
    const float* __restrict__ bih, const float* __restrict__ bhh,
    const float* __restrict__ h_cur,
    float* __restrict__ gi, float* __restrict__ gh0, float* __restrict__ gh1,
    int t)
{
    __shared__ float As[32 * 68];  // [kk][b], pad 68 (rows 16B-aligned)
    __shared__ float Ws[32 * 34];  // [kk][j], pad 34 (8B-aligned pairs)
    __shared__ int ids[B_];
    const int tid = threadIdx.x;
    const int z = blockIdx.y;
    const int j0 = blockIdx.x * 32;
    const int tx = tid & 15;   // j-pair: j = j0 + 2*tx
    const int ty = tid >> 4;   // b-group: b = 4*ty .. 4*ty+3
    float accI[4][2], accH[4][2];
#pragma unroll
    for (int i = 0; i < 4; ++i) { accI[i][0]=0.f; accI[i][1]=0.f; accH[i][0]=0.f; accH[i][1]=0.f; }
    if (tid < B_) ids[tid] = (t == 0) ? 0 : targets[tid * T_ + t - 1];
    __syncthreads();

    if (z == 0) {
        // ---- E part: K = 256 ----
        for (int c = 0; c < 8; ++c) {
            int k0 = c * 32;
#pragma unroll
            for (int r = 0; r < 2; ++r) {
                int lin = tid + 256 * r;          // 512 float4 slots (64 b x 8 k4)
                int k4 = lin & 7, b = lin >> 3;
                float4 v = *(const float4*)&E[(size_t)ids[b] * WE_ + k0 + k4 * 4];
                int kk = k4 * 4;
                As[(kk + 0) * 68 + b] = v.x; As[(kk + 1) * 68 + b] = v.y;
                As[(kk + 2) * 68 + b] = v.z; As[(kk + 3) * 68 + b] = v.w;
            }
            {
                int k4 = tid & 7, jj = tid >> 3;  // 32 j x 8 k4
                float4 v = *(const float4*)&Wih[(size_t)(j0 + jj) * WE_ + k0 + k4 * 4];
                int kk = k4 * 4;
                Ws[(kk + 0) * 34 + jj] = v.x; Ws[(kk + 1) * 34 + jj] = v.y;
                Ws[(kk + 2) * 34 + jj] = v.z; Ws[(kk + 3) * 34 + jj] = v.w;
            }
            __syncthreads();
#pragma unroll
            for (int kk = 0; kk < 32; ++kk) {
                float4 a = *(const float4*)&As[kk * 68 + ty * 4];
                float2 w = *(const float2*)&Ws[kk * 34 + tx * 2];
                accI[0][0] += a.x * w.x; accI[0][1] += a.x * w.y;
                accI[1][0] += a.y * w.x; accI[1][1] += a.y * w.y;
                accI[2][0] += a.z * w.x; accI[2][1] += a.z * w.y;
                accI[3][0] += a.w * w.x; accI[3][1] += a.w * w.y;
            }
            __syncthreads();
        }
    }

    const int c_lo = (z == 0) ? 0 : 12;
    const int c_hi = (z == 0) ? 12 : 32;
    for (int c = c_lo; c < c_hi; ++c) {
        int k0 = c * 32;
#pragma unroll
        for (int r = 0; r < 2; ++r) {
            int lin = tid + 256 * r;
            int k4 = lin & 7, b = lin >> 3;
            float4 v = *(const float4*)&h_cur[(size_t)b * H_ + k0 + k4 * 4];
            int kk = k4 * 4;
            As[(kk + 0) * 68 + b] = v.x; As[(kk + 1) * 68 + b] = v.y;
            As[(kk + 2) * 68 + b] = v.z; As[(kk + 3) * 68 + b] = v.w;
        }
        {
            int k4 = tid & 7, jj = tid >> 3;
            float4 v = *(const float4*)&Whh[(size_t)(j0 + jj) * H_ + k0 + k4 * 4];
            int kk = k4 * 4;
            Ws[(kk + 0) * 34 + jj] = v.x; Ws[(kk + 1) * 34 + jj] = v.y;
            Ws[(kk + 2) * 34 + jj] = v.z; Ws[(kk + 3) * 34 + jj] = v.w;
        }
        __syncthreads();
#pragma unroll
        for (int kk = 0; kk < 32; ++kk) {
            float4 a = *(const float4*)&As[kk * 68 + ty * 4];
            float2 w = *(const float2*)&Ws[kk * 34 + tx * 2];
            accH[0][0] += a.x * w.x; accH[0][1] += a.x * w.y;
            accH[1][0] += a.y * w.x; accH[1][1] += a.y * w.y;
            accH[2][0] += a.z * w.x; accH[2][1] += a.z * w.y;
            accH[3][0] += a.w * w.x; accH[3][1] += a.w * w.y;
        }
        __syncthreads();
    }

#pragma unroll
    for (int p = 0; p < 2; ++p) {
        int j = j0 + tx * 2 + p;
        if (z == 0) {
            float vi = bih[j], vh = bhh[j];
#pragma unroll
            for (int i = 0; i < 4; ++i) {
                int b = ty * 4 + i;
                gi[(size_t)b * G3_ + j]  = accI[i][p] + vi;
                gh0[(size_t)b * G3_ + j] = accH[i][p] + vh;
            }
        } else {
#pragma unroll
            for (int i = 0; i < 4; ++i) {
                int b = ty * 4 + i;
                gh1[(size_t)b * G3_ + j] = accH[i][p];
            }
        }
    }
}

// Fused GRU update + attention scores. grid (4 t-chunks, 64 b).
// Each block recomputes h_new[b] (cheap, 4x redundant), tc==0 also publishes it.
__global__ __launch_bounds__(256) void k_score_h(
    const float* __restrict__ gi, const float* __restrict__ gh0, const float* __restrict__ gh1,
    const float* __restrict__ h_prev, const float* __restrict__ enc,
    float* __restrict__ e_raw, float* __restrict__ h_next,
    __hip_bfloat16* __restrict__ Xb, int t, int use_x)
{
    __shared__ float hs[H_];
    const int b = blockIdx.y;
    const int tc = blockIdx.x;
    const int tid = threadIdx.x;
    // Phase A: GRU gate math for 4 elements per thread
#pragma unroll
    for (int i = 0; i < 4; ++i) {
        int k = i * 256 + tid;
        size_t o = (size_t)b * G3_ + k;
        float ir = gi[o], iz = gi[o + H_], in = gi[o + 2 * H_];
        float hr = gh0[o] + gh1[o];
        float hz = gh0[o + H_] + gh1[o + H_];
        float hn = gh0[o + 2 * H_] + gh1[o + 2 * H_];
        float r = sigmoidf_(ir + hr);
        float z = sigmoidf_(iz + hz);
        float n = tanhf(in + r * hn);
        float hv = (1.f - z) * n + z * h_prev[(size_t)b * H_ + k];
        hs[k] = hv;
        if (tc == 0) {
            h_next[(size_t)b * H_ + k] = hv;
            if (use_x) Xb[((size_t)b * T_ + t) * C_ + k] = __float2bfloat16(hv);
        }
    }
    __syncthreads();
    // Phase B: scores for 64 t' per block, 4 lanes per dot
    const int tl = tid >> 2, part = tid & 3;
    const int tt = tc * 64 + tl;
    const float4* row = (const float4*)(enc + ((size_t)b * T_ + tt) * H_);
    const float4* hv4 = (const float4*)hs;
    float acc = 0.f;
#pragma unroll 8
    for (int i = 0; i < 64; ++i) {
        float4 a = row[part * 64 + i];
        float4 x = hv4[part * 64 + i];
        acc += a.x * x.x + a.y * x.y + a.z * x.z + a.w * x.w;
    }
    acc += __shfl_xor(acc, 1);
    acc += __shfl_xor(acc, 2);
    if (part == 0) e_raw[(size_t)b * T_ + tt] = acc;
}

// Masked softmax (recomputed per block) + context slice. grid (4 k-quarters, 64 b).
__global__ __launch_bounds__(256) void k_ctx(
    const float* __restrict__ e_raw, const float* __restrict__ maskf,
    const float* __restrict__ enc, float* __restrict__ cvec,
    __hip_bfloat16* __restrict__ Xb, int t, int use_x)
{
    __shared__ float al[T_];
    __shared__ float red[256];
    const int b = blockIdx.y, q = blockIdx.x, tid = threadIdx.x;
    float e = (maskf[(size_t)b * T_ + tid] > 0.5f) ? e_raw[(size_t)b * T_ + tid] : -INFINITY;
    red[tid] = e; __syncthreads();
    for (int s = 128; s > 0; s >>= 1) { if (tid < s) red[tid] = fmaxf(red[tid], red[tid + s]); __syncthreads(); }
    float mx = red[0]; __syncthreads();
    float p = expf(e - mx);
    red[tid] = p; __syncthreads();
    for (int s = 128; s > 0; s >>= 1) { if (tid < s) red[tid] += red[tid + s]; __syncthreads(); }
    float denom = red[0];
    al[tid] = p / denom;
    __syncthreads();
    const int k = q * 256 + tid;
    float acc = 0.f;
#pragma unroll 8
    for (int tt2 = 0; tt2 < T_; ++tt2) {
        acc += al[tt2] * enc[((size_t)b * T_ + tt2) * H_ + k];
    }
    if (use_x) Xb[((size_t)b * T_ + t) * C_ + H_ + k] = __float2bfloat16(acc);
    else       cvec[(size_t)b * H_ + k] = acc;
}

// FALLBACK (small ws): per-step fp32 logits GEMM (round-1 version).
__global__ __launch_bounds__(256) void k_logits(
    const float* __restrict__ h, const float* __restrict__ cvec,
    const float* __restrict__ Wout, const float* __restrict__ bout,
    float* __restrict__ out, int t)
{
    __shared__ float As[32 * 68];
    __shared__ float Ws[32 * 33];
    const int tid = threadIdx.x;
    const int j0 = blockIdx.x * 32;
    const int tx = tid & 31;
    const int ty = tid >> 5;
    float acc[8];
#pragma unroll
    for (int i = 0; i < 8; ++i) acc[i] = 0.f;
    for (int c = 0; c < 64; ++c) {
        int k0 = c * 32;
        const float* Ap = (k0 < H_) ? (h + k0) : (cvec + (k0 - H_));
#pragma unroll
        for (int r = 0; r < 2; ++r) {
            int lin = tid + 256 * r;
            int k4 = lin & 7, b = lin >> 3;
            float4 v = *(const float4*)&Ap[(size_t)b * H_ + k4 * 4];
            int kk = k4 * 4;
            As[(kk + 0) * 68 + b] = v.x; As[(kk + 1) * 68 + b] = v.y;
            As[(kk + 2) * 68 + b] = v.z; As[(kk + 3) * 68 + b] = v.w;
        }
        {
            int k4 = tid & 7, jj = tid >> 3;
            float4 v = *(const float4*)&Wout[(size_t)(j0 + jj) * (2 * H_) + k0 + k4 * 4];
            int kk = k4 * 4;
            Ws[(kk + 0) * 33 + jj] = v.x; Ws[(kk + 1) * 33 + jj] = v.y;
            Ws[(kk + 2) * 33 + jj] = v.z; Ws[(kk + 3) * 33 + jj] = v.w;
        }
        __syncthreads();
#pragma unroll
        for (int kk = 0; kk < 32; ++kk) {
            float w = Ws[kk * 33 + tx];
#pragma unroll
            for (int i = 0; i < 8; ++i) acc[i] += As[kk * 68 + ty * 8 + i] * w;
        }
        __syncthreads();
    }
    float bo = bout[j0 + tx];
#pragma unroll
    for (int i = 0; i < 8; ++i) {
        int b = ty * 8 + i;
        out[((size_t)b * T_ + t) * C_ + j0 + tx] = acc[i] + bo;
    }
}

// FAST path: one big bf16 MFMA GEMM at the end.
// out[r][j] = sum_k Xb[r][k]*Wb[j][k] + bout[j]; M=16384, N=2048, K=2048.
// 128x128 block tile, 4 waves of 64x64 (4x4 16x16x32 MFMA tiles).
__global__ __launch_bounds__(256) void k_final(
    const __hip_bfloat16* __restrict__ Xb, const __hip_bfloat16* __restrict__ Wb,
    const float* __restrict__ bout, float* __restrict__ out)
{
    __shared__ __hip_bfloat16 As[128 * 40];  // row stride 40 bf16 = 80 B (16B-aligned, bank-spread)
    __shared__ __hip_bfloat16 Bs[128 * 40];
    const int tid = threadIdx.x;
    const int gr0 = blockIdx.x * 128;  // M offset
    const int j0  = blockIdx.y * 128;  // N offset
    const int lane = tid & 63, wave = tid >> 6;
    const int wm = (wave & 1) * 64, wn = (wave >> 1) * 64;
    const int ml = lane & 15, quad = lane >> 4;
    f32x4 acc[4][4];
#pragma unroll
    for (int a = 0; a < 4; ++a)
#pragma unroll
        for (int b = 0; b < 4; ++b) acc[a][b] = (f32x4){0.f, 0.f, 0.f, 0.f};

    for (int kc = 0; kc < 64; ++kc) {
#pragma unroll
        for (int r = 0; r < 2; ++r) {
            int s = tid + 256 * r;          // 512 slots of 16B per operand
            int row = s >> 2, kq = s & 3;
            *(uint4*)&As[row * 40 + kq * 8] =
                *(const uint4*)&Xb[(size_t)(gr0 + row) * 2048 + kc * 32 + kq * 8];
            *(uint4*)&Bs[row * 40 + kq * 8] =
                *(const uint4*)&Wb[(size_t)(j0 + row) * 2048 + kc * 32 + kq * 8];
        }
        __syncthreads();
        short8 af[4], bf[4];
#pragma unroll
        for (int mt = 0; mt < 4; ++mt)
            af[mt] = *(const short8*)&As[(wm + mt * 16 + ml) * 40 + quad * 8];
#pragma unroll
        for (int nt = 0; nt < 4; ++nt)
            bf[nt] = *(const short8*)&Bs[(wn + nt * 16 + ml) * 40 + quad * 8];
#pragma unroll
        for (int mt = 0; mt < 4; ++mt)
#pragma unroll
            for (int nt = 0; nt < 4; ++nt)
                acc[mt][nt] = __builtin_amdgcn_mfma_f32_16x16x32_bf16(af[mt], bf[nt], acc[mt][nt], 0, 0, 0);
        __syncthreads();
    }
#pragma unroll
    for (int nt = 0; nt < 4; ++nt) {
        int j = j0 + wn + nt * 16 + ml;
        float bo = bout[j];
#pragma unroll
        for (int mt = 0; mt < 4; ++mt) {
#pragma unroll
            for (int reg = 0; reg < 4; ++reg) {
                int r = gr0 + wm + mt * 16 + quad * 4 + reg;
                out[(size_t)r * 2048 + j] = acc[mt][nt][reg] + bo;
            }
        }
    }
}

extern "C" void kernel_launch(void* const* d_in, const int* in_sizes, int n_in,
                              void* d_out, int out_size, void* d_ws, size_t ws_size,
                              hipStream_t stream)
{
    const float* enc     = (const float*)d_in[0];
    const unsigned char* mask = (const unsigned char*)d_in[1];
    const int*   targets = (const int*)d_in[2];
    const float* E       = (const float*)d_in[3];
    const float* Wih     = (const float*)d_in[4];
    const float* Whh     = (const float*)d_in[5];
    const float* bih     = (const float*)d_in[6];
    const float* bhh     = (const float*)d_in[7];
    const float* Wout    = (const float*)d_in[8];
    const float* bout    = (const float*)d_in[9];
    float* out = (float*)d_out;

    float* ws    = (float*)d_ws;
    float* hbuf  = ws;                 // 2 x 65536 (ping-pong)
    float* gi    = ws + 131072;        // 196608
    float* gh0   = gi + 196608;        // 196608
    float* gh1   = gh0 + 196608;       // 196608
    float* e_raw = gh1 + 196608;       // 16384
    float* maskf = e_raw + 16384;      // 16384
    float* cvec  = maskf + 16384;      // 65536
    __hip_bfloat16* Wb = (__hip_bfloat16*)(ws + 819200);  // 2048*2048
    __hip_bfloat16* Xb = Wb + 4194304;                    // 16384*2048

    const size_t need = 819200ull * 4 + (4194304ull + 33554432ull) * 2;  // ~79 MB
    const int fast = (ws_size >= need) ? 1 : 0;

    k_maskprep<<<64, 256, 0, stream>>>(mask, maskf);
    k_hinit<<<256, 256, 0, stream>>>(enc, hbuf);
    if (fast) k_wprep<<<4096, 256, 0, stream>>>(Wout, Wb);

    for (int t = 0; t < T_; ++t) {
        float* h_cur  = hbuf + (t & 1) * 65536;
        float* h_next = hbuf + ((t + 1) & 1) * 65536;
        k_gates<<<dim3(96, 2), 256, 0, stream>>>(E, targets, Wih, Whh, bih, bhh,
                                                 h_cur, gi, gh0, gh1, t);
        k_score_h<<<dim3(4, 64), 256, 0, stream>>>(gi, gh0, gh1, h_cur, enc,
                                                   e_raw, h_next, Xb, t, fast);
        k_ctx<<<dim3(4, 64), 256, 0, stream>>>(e_raw, maskf, enc, cvec, Xb, t, fast);
        if (!fast)
            k_logits<<<64, 256, 0, stream>>>(h_next, cvec, Wout, bout, out, t);
    }
    if (fast)
        k_final<<<dim3(128, 16), 256, 0, stream>>>(Xb, Wb, bout, out);
}

// Round 3
// 6161.858 us; speedup vs baseline: 7.2275x; 2.4259x over previous
//
#include <hip/hip_runtime.h>
#include <hip/hip_bf16.h>
#include <math.h>

#define B_ 64
#define T_ 256
#define C_ 2048
#define WE_ 256
#define H_ 1024
#define G3_ 3072

typedef __attribute__((ext_vector_type(8))) short short8;
typedef __attribute__((ext_vector_type(4))) float f32x4;

__device__ __forceinline__ float sigmoidf_(float x) { return 1.f / (1.f + expf(-x)); }

__device__ __forceinline__ unsigned short f2bf(float v) {
    union { float f; unsigned int u; } x; x.f = v;
    unsigned int r = x.u + 0x7fffu + ((x.u >> 16) & 1u);
    return (unsigned short)(r >> 16);
}
__device__ __forceinline__ float bf2f(unsigned short h) {
    union { unsigned int u; float f; } x; x.u = ((unsigned int)h) << 16;
    return x.f;
}

// ---------------- shared prep ----------------

__global__ void k_maskprep(const unsigned char* __restrict__ m, float* __restrict__ mf) {
    int idx = blockIdx.x * 256 + threadIdx.x;  // 0..16383
    bool bytemode = (m[1] != 0);               // mask[0][1] always true (words_num>=128)
    unsigned char v = bytemode ? m[idx] : m[(size_t)idx * 4];
    mf[idx] = v ? 1.f : 0.f;
}

// ---------------- FULL path ----------------

__global__ void k_hinit2(const float* __restrict__ enc, float* __restrict__ h32,
                         unsigned short* __restrict__ h0h, unsigned short* __restrict__ h0l) {
    int idx = blockIdx.x * 256 + threadIdx.x;  // 0..65535
    int b = idx >> 10, k = idx & (H_ - 1);
    float v = enc[((size_t)b * T_ + (T_ - 1)) * H_ + k];
    h32[idx] = v;
    unsigned short hi = f2bf(v);
    h0h[idx] = hi;
    h0l[idx] = f2bf(v - bf2f(hi));
}

// Wg[j][k] (3072 x 1280): k<256 -> Wih[j][k], k>=256 -> Whh[j][k-256]; hi/lo bf16.
__global__ void k_wgprep(const float* __restrict__ Wih, const float* __restrict__ Whh,
                         unsigned short* __restrict__ Wgh, unsigned short* __restrict__ Wgl) {
    int row = blockIdx.x;          // 0..3071
    int c4 = threadIdx.x;          // 0..319
    int col = c4 * 4;
    float4 v = (col < 256) ? *(const float4*)&Wih[(size_t)row * 256 + col]
                           : *(const float4*)&Whh[(size_t)row * 1024 + col - 256];
    unsigned short h[4], l[4];
    float vv[4] = {v.x, v.y, v.z, v.w};
#pragma unroll
    for (int i = 0; i < 4; ++i) { h[i] = f2bf(vv[i]); l[i] = f2bf(vv[i] - bf2f(h[i])); }
    size_t o = (size_t)row * 1280 + col;
    *(uint2*)&Wgh[o] = *(const uint2*)h;
    *(uint2*)&Wgl[o] = *(const uint2*)l;
}

// Xe[t][b][e] hi/lo bf16: embedding rows gathered for all steps.
__global__ void k_xemb(const float* __restrict__ E, const int* __restrict__ targets,
                       unsigned short* __restrict__ Xeh, unsigned short* __restrict__ Xel) {
    int t = blockIdx.x, b = blockIdx.y, l = threadIdx.x;  // l 0..63
    int id = (t == 0) ? 0 : targets[b * T_ + t - 1];
    float4 v = *(const float4*)&E[(size_t)id * 256 + l * 4];
    unsigned short h[4], lo[4];
    float vv[4] = {v.x, v.y, v.z, v.w};
#pragma unroll
    for (int i = 0; i < 4; ++i) { h[i] = f2bf(vv[i]); lo[i] = f2bf(vv[i] - bf2f(h[i])); }
    size_t o = (size_t)t * 16384 + (size_t)b * 256 + l * 4;
    *(uint2*)&Xeh[o] = *(const uint2*)h;
    *(uint2*)&Xel[o] = *(const uint2*)lo;
}

__global__ void k_encprep(const float* __restrict__ enc,
                          unsigned short* __restrict__ ench, unsigned short* __restrict__ encl) {
    size_t i4 = (size_t)blockIdx.x * 256 + threadIdx.x;   // 0..4194303
    float4 v = *(const float4*)&enc[i4 * 4];
    unsigned short h[4], l[4];
    float vv[4] = {v.x, v.y, v.z, v.w};
#pragma unroll
    for (int i = 0; i < 4; ++i) { h[i] = f2bf(vv[i]); l[i] = f2bf(vv[i] - bf2f(h[i])); }
    *(uint2*)&ench[i4 * 4] = *(const uint2*)h;
    *(uint2*)&encl[i4 * 4] = *(const uint2*)l;
}

// One recurrence step: gates GEMM (bf16x2 MFMA, M=64 b, N=48 cols = {r,z,n}x16 j, K=1280)
// + GRU epilogue. grid 64 blocks (j-chunks of 16), 256 threads (4 waves, wave = 16 b's).
__global__ __launch_bounds__(256) void k_step(
    const unsigned short* __restrict__ Xeh_t, const unsigned short* __restrict__ Xel_t,
    const unsigned short* __restrict__ Aph, const unsigned short* __restrict__ Apl, int ap_stride,
    const unsigned short* __restrict__ Wgh, const unsigned short* __restrict__ Wgl,
    const float* __restrict__ bih, const float* __restrict__ bhh,
    const float* __restrict__ h_prev32, float* __restrict__ h_next32,
    unsigned short* __restrict__ HhO, unsigned short* __restrict__ HlO)
{
    __shared__ unsigned short Ah[64 * 40], Al[64 * 40], Bh[48 * 40], Bl[48 * 40];
    __shared__ float bR[16], bZ[16], bNX[16], bNH[16];
    const int tid = threadIdx.x;
    const int j0 = blockIdx.x * 16;
    const int wave = tid >> 6, lane = tid & 63;
    const int ml = lane & 15, quad = lane >> 4;
    if (tid < 16) {
        int j = j0 + tid;
        bR[tid] = bih[j] + bhh[j];
        bZ[tid] = bih[1024 + j] + bhh[1024 + j];
        bNX[tid] = bih[2048 + j];
        bNH[tid] = bhh[2048 + j];
    }
    f32x4 accR = {0,0,0,0}, accZ = {0,0,0,0}, accNX = {0,0,0,0}, accNH = {0,0,0,0};
    const int ar = tid >> 2, aq = tid & 3;
    uint4 rAh = {0,0,0,0}, rAl = {0,0,0,0}, rBh = {0,0,0,0}, rBl = {0,0,0,0};
    {   // prefetch chunk 0 (x region)
        size_t off = (size_t)ar * 256 + aq * 8;
        rAh = *(const uint4*)&Xeh_t[off];
        rAl = *(const uint4*)&Xel_t[off];
    }
    if (tid < 192) {
        int g = ar >> 4, jj = ar & 15;
        size_t off = (size_t)(g * 1024 + j0 + jj) * 1280 + aq * 8;
        rBh = *(const uint4*)&Wgh[off];
        rBl = *(const uint4*)&Wgl[off];
    }
    for (int c = 0; c < 40; ++c) {
        *(uint4*)&Ah[ar * 40 + aq * 8] = rAh;
        *(uint4*)&Al[ar * 40 + aq * 8] = rAl;
        if (tid < 192) {
            *(uint4*)&Bh[ar * 40 + aq * 8] = rBh;
            *(uint4*)&Bl[ar * 40 + aq * 8] = rBl;
        }
        __syncthreads();
        if (c + 1 < 40) {
            int k0 = (c + 1) * 32;
            if (k0 < 256) {
                size_t off = (size_t)ar * 256 + k0 + aq * 8;
                rAh = *(const uint4*)&Xeh_t[off];
                rAl = *(const uint4*)&Xel_t[off];
            } else {
                size_t off = (size_t)ar * ap_stride + (k0 - 256) + aq * 8;
                rAh = *(const uint4*)&Aph[off];
                rAl = *(const uint4*)&Apl[off];
            }
            if (tid < 192) {
                int g = ar >> 4, jj = ar & 15;
                size_t off = (size_t)(g * 1024 + j0 + jj) * 1280 + k0 + aq * 8;
                rBh = *(const uint4*)&Wgh[off];
                rBl = *(const uint4*)&Wgl[off];
            }
        }
        short8 ah = *(const short8*)&Ah[(wave * 16 + ml) * 40 + quad * 8];
        short8 al = *(const short8*)&Al[(wave * 16 + ml) * 40 + quad * 8];
        short8 bh0 = *(const short8*)&Bh[(0 * 16 + ml) * 40 + quad * 8];
        short8 bl0 = *(const short8*)&Bl[(0 * 16 + ml) * 40 + quad * 8];
        short8 bh1 = *(const short8*)&Bh[(1 * 16 + ml) * 40 + quad * 8];
        short8 bl1 = *(const short8*)&Bl[(1 * 16 + ml) * 40 + quad * 8];
        short8 bh2 = *(const short8*)&Bh[(2 * 16 + ml) * 40 + quad * 8];
        short8 bl2 = *(const short8*)&Bl[(2 * 16 + ml) * 40 + quad * 8];
        accR = __builtin_amdgcn_mfma_f32_16x16x32_bf16(ah, bh0, accR, 0, 0, 0);
        accR = __builtin_amdgcn_mfma_f32_16x16x32_bf16(ah, bl0, accR, 0, 0, 0);
        accR = __builtin_amdgcn_mfma_f32_16x16x32_bf16(al, bh0, accR, 0, 0, 0);
        accZ = __builtin_amdgcn_mfma_f32_16x16x32_bf16(ah, bh1, accZ, 0, 0, 0);
        accZ = __builtin_amdgcn_mfma_f32_16x16x32_bf16(ah, bl1, accZ, 0, 0, 0);
        accZ = __builtin_amdgcn_mfma_f32_16x16x32_bf16(al, bh1, accZ, 0, 0, 0);
        if (c < 8) {
            accNX = __builtin_amdgcn_mfma_f32_16x16x32_bf16(ah, bh2, accNX, 0, 0, 0);
            accNX = __builtin_amdgcn_mfma_f32_16x16x32_bf16(ah, bl2, accNX, 0, 0, 0);
            accNX = __builtin_amdgcn_mfma_f32_16x16x32_bf16(al, bh2, accNX, 0, 0, 0);
        } else {
            accNH = __builtin_amdgcn_mfma_f32_16x16x32_bf16(ah, bh2, accNH, 0, 0, 0);
            accNH = __builtin_amdgcn_mfma_f32_16x16x32_bf16(ah, bl2, accNH, 0, 0, 0);
            accNH = __builtin_amdgcn_mfma_f32_16x16x32_bf16(al, bh2, accNH, 0, 0, 0);
        }
        __syncthreads();
    }
    // GRU epilogue: lane owns (4 b's) x (1 j)
    int j = j0 + ml;
    float brv = bR[ml], bzv = bZ[ml], bnxv = bNX[ml], bnhv = bNH[ml];
#pragma unroll
    for (int reg = 0; reg < 4; ++reg) {
        int b = wave * 16 + quad * 4 + reg;
        float r = sigmoidf_(accR[reg] + brv);
        float z = sigmoidf_(accZ[reg] + bzv);
        float n = tanhf((accNX[reg] + bnxv) + r * (accNH[reg] + bnhv));
        float hp = h_prev32[(size_t)b * 1024 + j];
        float hv = (1.f - z) * n + z * hp;
        h_next32[(size_t)b * 1024 + j] = hv;
        unsigned short hi = f2bf(hv);
        HhO[(size_t)b * 262144 + j] = hi;
        HlO[(size_t)b * 262144 + j] = f2bf(hv - bf2f(hi));
    }
}

// Batched scores: e[b][t][t'] = h_t[b] . enc[b][t'], bf16x2 MFMA.
// grid (4, 64): t-tile 128 x t'-tile 128, K=1024 (32 chunks).
__global__ __launch_bounds__(256) void k_scoresK(
    const unsigned short* __restrict__ Hh, const unsigned short* __restrict__ Hl,
    const unsigned short* __restrict__ ench, const unsigned short* __restrict__ encl,
    float* __restrict__ e_all)
{
    __shared__ unsigned short Ahs[128 * 40], Als[128 * 40], Bhs[128 * 40], Bls[128 * 40];
    const int tid = threadIdx.x;
    const int b = blockIdx.y;
    const int t0 = (blockIdx.x & 1) * 128, p0 = (blockIdx.x >> 1) * 128;
    const int lane = tid & 63, wave = tid >> 6;
    const int wm = (wave & 1) * 64, wn = (wave >> 1) * 64;
    const int ml = lane & 15, quad = lane >> 4;
    const unsigned short* Ahp = Hh + (size_t)b * 262144;
    const unsigned short* Alp = Hl + (size_t)b * 262144;
    const unsigned short* Bhp = ench + (size_t)b * 262144;
    const unsigned short* Blp = encl + (size_t)b * 262144;
    f32x4 acc[4][4];
#pragma unroll
    for (int a = 0; a < 4; ++a)
#pragma unroll
        for (int c = 0; c < 4; ++c) acc[a][c] = (f32x4){0.f, 0.f, 0.f, 0.f};

    for (int kc = 0; kc < 32; ++kc) {
#pragma unroll
        for (int r2 = 0; r2 < 2; ++r2) {
            int s = tid + 256 * r2;
            int row = s >> 2, q = s & 3;
            size_t ga = (size_t)(t0 + row) * 1024 + kc * 32 + q * 8;
            size_t gb = (size_t)(p0 + row) * 1024 + kc * 32 + q * 8;
            *(uint4*)&Ahs[row * 40 + q * 8] = *(const uint4*)&Ahp[ga];
            *(uint4*)&Als[row * 40 + q * 8] = *(const uint4*)&Alp[ga];
            *(uint4*)&Bhs[row * 40 + q * 8] = *(const uint4*)&Bhp[gb];
            *(uint4*)&Bls[row * 40 + q * 8] = *(const uint4*)&Blp[gb];
        }
        __syncthreads();
        short8 ah[4], al[4], bh[4], bl[4];
#pragma unroll
        for (int mt = 0; mt < 4; ++mt) {
            ah[mt] = *(const short8*)&Ahs[(wm + mt * 16 + ml) * 40 + quad * 8];
            al[mt] = *(const short8*)&Als[(wm + mt * 16 + ml) * 40 + quad * 8];
        }
#pragma unroll
        for (int nt = 0; nt < 4; ++nt) {
            bh[nt] = *(const short8*)&Bhs[(wn + nt * 16 + ml) * 40 + quad * 8];
            bl[nt] = *(const short8*)&Bls[(wn + nt * 16 + ml) * 40 + quad * 8];
        }
#pragma unroll
        for (int mt = 0; mt < 4; ++mt)
#pragma unroll
            for (int nt = 0; nt < 4; ++nt) {
                acc[mt][nt] = __builtin_amdgcn_mfma_f32_16x16x32_bf16(ah[mt], bh[nt], acc[mt][nt], 0, 0, 0);
                acc[mt][nt] = __builtin_amdgcn_mfma_f32_16x16x32_bf16(ah[mt], bl[nt], acc[mt][nt], 0, 0, 0);
                acc[mt][nt] = __builtin_amdgcn_mfma_f32_16x16x32_bf16(al[mt], bh[nt], acc[mt][nt], 0, 0, 0);
            }
        __syncthreads();
    }
#pragma unroll
    for (int mt = 0; mt < 4; ++mt)
#pragma unroll
        for (int nt = 0; nt < 4; ++nt)
#pragma unroll
            for (int reg = 0; reg < 4; ++reg) {
                int t = t0 + wm + mt * 16 + quad * 4 + reg;
                int p = p0 + wn + nt * 16 + ml;
                e_all[((size_t)b * 256 + t) * 256 + p] = acc[mt][nt][reg];
            }
}

// Masked softmax: one wave per (b,t) row; alpha -> bf16.
__global__ __launch_bounds__(256) void k_softmaxK(
    const float* __restrict__ e_all, const float* __restrict__ maskf,
    unsigned short* __restrict__ Ab)
{
    const int tid = threadIdx.x;
    const int ridx = blockIdx.x * 4 + (tid >> 6);
    const int lane = tid & 63;
    const int b = ridx >> 8, t = ridx & 255;
    const float* er = e_all + ((size_t)b * 256 + t) * 256;
    const float* mr = maskf + (size_t)b * 256;
    float v[4];
#pragma unroll
    for (int i = 0; i < 4; ++i) {
        int p = lane + 64 * i;
        v[i] = (mr[p] > 0.5f) ? er[p] : -INFINITY;
    }
    float m = fmaxf(fmaxf(v[0], v[1]), fmaxf(v[2], v[3]));
#pragma unroll
    for (int off = 32; off > 0; off >>= 1) m = fmaxf(m, __shfl_xor(m, off));
    float s = 0.f;
#pragma unroll
    for (int i = 0; i < 4; ++i) { v[i] = expf(v[i] - m); s += v[i]; }
#pragma unroll
    for (int off = 32; off > 0; off >>= 1) s += __shfl_xor(s, off);
    float inv = 1.f / s;
    unsigned short* arr = Ab + ((size_t)b * 256 + t) * 256;
#pragma unroll
    for (int i = 0; i < 4; ++i) arr[lane + 64 * i] = f2bf(v[i] * inv);
}

// Batched context: C[b][t][k] = sum_t' alpha[b][t][t'] * enc[b][t'][k], bf16 MFMA.
// grid (16, 64): t-tile 128 x k-tile 128, K=256 (8 chunks). B staged transposed in LDS.
__global__ __launch_bounds__(256) void k_contextK(
    const unsigned short* __restrict__ Ab, const unsigned short* __restrict__ ench,
    unsigned short* __restrict__ Cb)
{
    __shared__ unsigned short As[128 * 40];
    __shared__ unsigned short Bs[128 * 40];   // [k][t'] transposed
    const int tid = threadIdx.x;
    const int b = blockIdx.y;
    const int t0 = (blockIdx.x & 1) * 128;
    const int k0 = (blockIdx.x >> 1) * 128;
    const int lane = tid & 63, wave = tid >> 6;
    const int wm = (wave & 1) * 64, wn = (wave >> 1) * 64;
    const int ml = lane & 15, quad = lane >> 4;
    f32x4 acc[4][4];
#pragma unroll
    for (int a = 0; a < 4; ++a)
#pragma unroll
        for (int c = 0; c < 4; ++c) acc[a][c] = (f32x4){0.f, 0.f, 0.f, 0.f};

    for (int c = 0; c < 8; ++c) {
#pragma unroll
        for (int r2 = 0; r2 < 2; ++r2) {
            int s = tid + 256 * r2;
            int row = s >> 2, q = s & 3;
            *(uint4*)&As[row * 40 + q * 8] =
                *(const uint4*)&Ab[((size_t)b * 256 + t0 + row) * 256 + c * 32 + q * 8];
        }
        {   // transpose-stage enc tile: 32 t' x 128 k -> Bs[k][t']
            int tr = tid >> 3, kq = tid & 7;   // tr 0..31, kq 0..7
            const unsigned short* src =
                ench + ((size_t)b * 256 + c * 32 + tr) * 1024 + k0 + kq * 16;
            unsigned short tmp[16];
            *(uint4*)&tmp[0] = *(const uint4*)&src[0];
            *(uint4*)&tmp[8] = *(const uint4*)&src[8];
#pragma unroll
            for (int i = 0; i < 16; ++i)
                Bs[(kq * 16 + i) * 40 + tr] = tmp[i];
        }
        __syncthreads();
        short8 af[4], bf[4];
#pragma unroll
        for (int mt = 0; mt < 4; ++mt)
            af[mt] = *(const short8*)&As[(wm + mt * 16 + ml) * 40 + quad * 8];
#pragma unroll
        for (int nt = 0; nt < 4; ++nt)
            bf[nt] = *(const short8*)&Bs[(wn + nt * 16 + ml) * 40 + quad * 8];
#pragma unroll
        for (int mt = 0; mt < 4; ++mt)
#pragma unroll
            for (int nt = 0; nt < 4; ++nt)
                acc[mt][nt] = __builtin_amdgcn_mfma_f32_16x16x32_bf16(af[mt], bf[nt], acc[mt][nt], 0, 0, 0);
        __syncthreads();
    }
#pragma unroll
    for (int mt = 0; mt < 4; ++mt)
#pragma unroll
        for (int nt = 0; nt < 4; ++nt)
#pragma unroll
            for (int reg = 0; reg < 4; ++reg) {
                int t = t0 + wm + mt * 16 + quad * 4 + reg;
                int k = k0 + wn + nt * 16 + ml;
                Cb[((size_t)b * 256 + t) * 1024 + k] = f2bf(acc[mt][nt][reg]);
            }
}

// Final logits GEMM: out[r][j] = [Hh|Cb][r] . Wb[j] + bout[j]; M=16384,N=2048,K=2048.
__global__ __launch_bounds__(256) void k_finalK(
    const unsigned short* __restrict__ Hh, const unsigned short* __restrict__ Cb,
    const unsigned short* __restrict__ Wb,
    const float* __restrict__ bout, float* __restrict__ out)
{
    __shared__ unsigned short As[128 * 40];
    __shared__ unsigned short Bs[128 * 40];
    const int tid = threadIdx.x;
    const int gr0 = blockIdx.x * 128;
    const int j0  = blockIdx.y * 128;
    const int lane = tid & 63, wave = tid >> 6;
    const int wm = (wave & 1) * 64, wn = (wave >> 1) * 64;
    const int ml = lane & 15, quad = lane >> 4;
    f32x4 acc[4][4];
#pragma unroll
    for (int a = 0; a < 4; ++a)
#pragma unroll
        for (int c = 0; c < 4; ++c) acc[a][c] = (f32x4){0.f, 0.f, 0.f, 0.f};

    for (int kc = 0; kc < 64; ++kc) {
        const unsigned short* asrc = (kc < 32) ? Hh : Cb;
        int ko = (kc & 31) * 32;
#pragma unroll
        for (int r2 = 0; r2 < 2; ++r2) {
            int s = tid + 256 * r2;
            int row = s >> 2, q = s & 3;
            *(uint4*)&As[row * 40 + q * 8] =
                *(const uint4*)&asrc[(size_t)(gr0 + row) * 1024 + ko + q * 8];
            *(uint4*)&Bs[row * 40 + q * 8] =
                *(const uint4*)&Wb[(size_t)(j0 + row) * 2048 + kc * 32 + q * 8];
        }
        __syncthreads();
        short8 af[4], bf[4];
#pragma unroll
        for (int mt = 0; mt < 4; ++mt)
            af[mt] = *(const short8*)&As[(wm + mt * 16 + ml) * 40 + quad * 8];
#pragma unroll
        for (int nt = 0; nt < 4; ++nt)
            bf[nt] = *(const short8*)&Bs[(wn + nt * 16 + ml) * 40 + quad * 8];
#pragma unroll
        for (int mt = 0; mt < 4; ++mt)
#pragma unroll
            for (int nt = 0; nt < 4; ++nt)
                acc[mt][nt] = __builtin_amdgcn_mfma_f32_16x16x32_bf16(af[mt], bf[nt], acc[mt][nt], 0, 0, 0);
        __syncthreads();
    }
#pragma unroll
    for (int nt = 0; nt < 4; ++nt) {
        int j = j0 + wn + nt * 16 + ml;
        float bo = bout[j];
#pragma unroll
        for (int mt = 0; mt < 4; ++mt)
#pragma unroll
            for (int reg = 0; reg < 4; ++reg) {
                int r = gr0 + wm + mt * 16 + quad * 4 + reg;
                out[(size_t)r * 2048 + j] = acc[mt][nt][reg] + bo;
            }
    }
}

// ---------------- FALLBACK (round-2) path ----------------

__global__ void k_hinit(const float* __restrict__ enc, float* __restrict__ h) {
    int idx = blockIdx.x * 256 + threadIdx.x;
    int b = idx >> 10, k = idx & (H_ - 1);
    h[idx] = enc[((size_t)b * T_ + (T_ - 1)) * H_ + k];
}

__global__ void k_wprep(const float* __restrict__ Wout, __hip_bfloat16* __restrict__ Wb) {
    int i4 = blockIdx.x * 256 + threadIdx.x;
    float4 v = *(const float4*)&Wout[(size_t)i4 * 4];
    __attribute__((aligned(8))) __hip_bfloat16 tmp[4] = {
        __float2bfloat16(v.x), __float2bfloat16(v.y),
        __float2bfloat16(v.z), __float2bfloat16(v.w)};
    *(uint2*)&Wb[(size_t)i4 * 4] = *(const uint2*)tmp;
}

__global__ __launch_bounds__(256) void k_gates(
    const float* __restrict__ E, const int* __restrict__ targets,
    const float* __restrict__ Wih, const float* __restrict__ Whh,
    const float* __restrict__ bih, const float* __restrict__ bhh,
    const float* __restrict__ h_cur,
    float* __restrict__ gi, float* __restrict__ gh0, float* __restrict__ gh1,
    int t)
{
    __shared__ float As[32 * 68];
    __shared__ float Ws[32 * 34];
    __shared__ int ids[B_];
    const int tid = threadIdx.x;
    const int z = blockIdx.y;
    const int j0 = blockIdx.x * 32;
    const int tx = tid & 15;
    const int ty = tid >> 4;
    float accI[4][2], accH[4][2];
#pragma unroll
    for (int i = 0; i < 4; ++i) { accI[i][0]=0.f; accI[i][1]=0.f; accH[i][0]=0.f; accH[i][1]=0.f; }
    if (tid < B_) ids[tid] = (t == 0) ? 0 : targets[tid * T_ + t - 1];
    __syncthreads();
    if (z == 0) {
        for (int c = 0; c < 8; ++c) {
            int k0 = c * 32;
#pragma unroll
            for (int r = 0; r < 2; ++r) {
                int lin = tid + 256 * r;
                int k4 = lin & 7, b = lin >> 3;
                float4 v = *(const float4*)&E[(size_t)ids[b] * WE_ + k0 + k4 * 4];
                int kk = k4 * 4;
                As[(kk + 0) * 68 + b] = v.x; As[(kk + 1) * 68 + b] = v.y;
                As[(kk + 2) * 68 + b] = v.z; As[(kk + 3) * 68 + b] = v.w;
            }
            {
                int k4 = tid & 7, jj = tid >> 3;
                float4 v = *(const float4*)&Wih[(size_t)(j0 + jj) * WE_ + k0 + k4 * 4];
                int kk = k4 * 4;
                Ws[(kk + 0) * 34 + jj] = v.x; Ws[(kk + 1) * 34 + jj] = v.y;
                Ws[(kk + 2) * 34 + jj] = v.z; Ws[(kk + 3) * 34 + jj] = v.w;
            }
            __syncthreads();
#pragma unroll
            for (int kk = 0; kk < 32; ++kk) {
                float4 a = *(const float4*)&As[kk * 68 + ty * 4];
                float2 w = *(const float2*)&Ws[kk * 34 + tx * 2];
                accI[0][0] += a.x * w.x; accI[0][1] += a.x * w.y;
                accI[1][0] += a.y * w.x; accI[1][1] += a.y * w.y;
                accI[2][0] += a.z * w.x; accI[2][1] += a.z * w.y;
                accI[3][0] += a.w * w.x; accI[3][1] += a.w * w.y;
            }
            __syncthreads();
        }
    }
    const int c_lo = (z == 0) ? 0 : 12;
    const int c_hi = (z == 0) ? 12 : 32;
    for (int c = c_lo; c < c_hi; ++c) {
        int k0 = c * 32;
#pragma unroll
        for (int r = 0; r < 2; ++r) {
            int lin = tid + 256 * r;
            int k4 = lin & 7, b = lin >> 3;
            float4 v = *(const float4*)&h_cur[(size_t)b * H_ + k0 + k4 * 4];
            int kk = k4 * 4;
            As[(kk + 0) * 68 + b] = v.x; As[(kk + 1) * 68 + b] = v.y;
            As[(kk + 2) * 68 + b] = v.z; As[(kk + 3) * 68 + b] = v.w;
        }
        {
            int k4 = tid & 7, jj = tid >> 3;
            float4 v = *(const float4*)&Whh[(size_t)(j0 + jj) * H_ + k0 + k4 * 4];
            int kk = k4 * 4;
            Ws[(kk + 0) * 34 + jj] = v.x; Ws[(kk + 1) * 34 + jj] = v.y;
            Ws[(kk + 2) * 34 + jj] = v.z; Ws[(kk + 3) * 34 + jj] = v.w;
        }
        __syncthreads();
#pragma unroll
        for (int kk = 0; kk < 32; ++kk) {
            float4 a = *(const float4*)&As[kk * 68 + ty * 4];
            float2 w = *(const float2*)&Ws[kk * 34 + tx * 2];
            accH[0][0] += a.x * w.x; accH[0][1] += a.x * w.y;
            accH[1][0] += a.y * w.x; accH[1][1] += a.y * w.y;
            accH[2][0] += a.z * w.x; accH[2][1] += a.z * w.y;
            accH[3][0] += a.w * w.x; accH[3][1] += a.w * w.y;
        }
        __syncthreads();
    }
#pragma unroll
    for (int p = 0; p < 2; ++p) {
        int j = j0 + tx * 2 + p;
        if (z == 0) {
            float vi = bih[j], vh = bhh[j];
#pragma unroll
            for (int i = 0; i < 4; ++i) {
                int b = ty * 4 + i;
                gi[(size_t)b * G3_ + j]  = accI[i][p] + vi;
                gh0[(size_t)b * G3_ + j] = accH[i][p] + vh;
            }
        } else {
#pragma unroll
            for (int i = 0; i < 4; ++i) {
                int b = ty * 4 + i;
                gh1[(size_t)b * G3_ + j] = accH[i][p];
            }
        }
    }
}

__global__ __launch_bounds__(256) void k_score_h(
    const float* __restrict__ gi, const float* __restrict__ gh0, const float* __restrict__ gh1,
    const float* __restrict__ h_prev, const float* __restrict__ enc,
    float* __restrict__ e_raw, float* __restrict__ h_next,
    __hip_bfloat16* __restrict__ Xb, int t, int use_x)
{
    __shared__ float hs[H_];
    const int b = blockIdx.y;
    const int tc = blockIdx.x;
    const int tid = threadIdx.x;
#pragma unroll
    for (int i = 0; i < 4; ++i) {
        int k = i * 256 + tid;
        size_t o = (size_t)b * G3_ + k;
        float ir = gi[o], iz = gi[o + H_], in = gi[o + 2 * H_];
        float hr = gh0[o] + gh1[o];
        float hz = gh0[o + H_] + gh1[o + H_];
        float hn = gh0[o + 2 * H_] + gh1[o + 2 * H_];
        float r = sigmoidf_(ir + hr);
        float z = sigmoidf_(iz + hz);
        float n = tanhf(in + r * hn);
        float hv = (1.f - z) * n + z * h_prev[(size_t)b * H_ + k];
        hs[k] = hv;
        if (tc == 0) {
            h_next[(size_t)b * H_ + k] = hv;
            if (use_x) Xb[((size_t)b * T_ + t) * C_ + k] = __float2bfloat16(hv);
        }
    }
    __syncthreads();
    const int tl = tid >> 2, part = tid & 3;
    const int tt = tc * 64 + tl;
    const float4* row = (const float4*)(enc + ((size_t)b * T_ + tt) * H_);
    const float4* hv4 = (const float4*)hs;
    float acc = 0.f;
#pragma unroll 8
    for (int i = 0; i < 64; ++i) {
        float4 a = row[part * 64 + i];
        float4 x = hv4[part * 64 + i];
        acc += a.x * x.x + a.y * x.y + a.z * x.z + a.w * x.w;
    }
    acc += __shfl_xor(acc, 1);
    acc += __shfl_xor(acc, 2);
    if (part == 0) e_raw[(size_t)b * T_ + tt] = acc;
}

__global__ __launch_bounds__(256) void k_ctx(
    const float* __restrict__ e_raw, const float* __restrict__ maskf,
    const float* __restrict__ enc, float* __restrict__ cvec,
    __hip_bfloat16* __restrict__ Xb, int t, int use_x)
{
    __shared__ float al[T_];
    __shared__ float red[256];
    const int b = blockIdx.y, q = blockIdx.x, tid = threadIdx.x;
    float e = (maskf[(size_t)b * T_ + tid] > 0.5f) ? e_raw[(size_t)b * T_ + tid] : -INFINITY;
    red[tid] = e; __syncthreads();
    for (int s = 128; s > 0; s >>= 1) { if (tid < s) red[tid] = fmaxf(red[tid], red[tid + s]); __syncthreads(); }
    float mx = red[0]; __syncthreads();
    float p = expf(e - mx);
    red[tid] = p; __syncthreads();
    for (int s = 128; s > 0; s >>= 1) { if (tid < s) red[tid] += red[tid + s]; __syncthreads(); }
    float denom = red[0];
    al[tid] = p / denom;
    __syncthreads();
    const int k = q * 256 + tid;
    float acc = 0.f;
#pragma unroll 8
    for (int tt2 = 0; tt2 < T_; ++tt2) {
        acc += al[tt2] * enc[((size_t)b * T_ + tt2) * H_ + k];
    }
    if (use_x) Xb[((size_t)b * T_ + t) * C_ + H_ + k] = __float2bfloat16(acc);
    else       cvec[(size_t)b * H_ + k] = acc;
}

__global__ __launch_bounds__(256) void k_logits(
    const float* __restrict__ h, const float* __restrict__ cvec,
    const float* __restrict__ Wout, const float* __restrict__ bout,
    float* __restrict__ out, int t)
{
    __shared__ float As[32 * 68];
    __shared__ float Ws[32 * 33];
    const int tid = threadIdx.x;
    const int j0 = blockIdx.x * 32;
    const int tx = tid & 31;
    const int ty = tid >> 5;
    float acc[8];
#pragma unroll
    for (int i = 0; i < 8; ++i) acc[i] = 0.f;
    for (int c = 0; c < 64; ++c) {
        int k0 = c * 32;
        const float* Ap = (k0 < H_) ? (h + k0) : (cvec + (k0 - H_));
#pragma unroll
        for (int r = 0; r < 2; ++r) {
            int lin = tid + 256 * r;
            int k4 = lin & 7, b = lin >> 3;
            float4 v = *(const float4*)&Ap[(size_t)b * H_ + k4 * 4];
            int kk = k4 * 4;
            As[(kk + 0) * 68 + b] = v.x; As[(kk + 1) * 68 + b] = v.y;
            As[(kk + 2) * 68 + b] = v.z; As[(kk + 3) * 68 + b] = v.w;
        }
        {
            int k4 = tid & 7, jj = tid >> 3;
            float4 v = *(const float4*)&Wout[(size_t)(j0 + jj) * (2 * H_) + k0 + k4 * 4];
            int kk = k4 * 4;
            Ws[(kk + 0) * 33 + jj] = v.x; Ws[(kk + 1) * 33 + jj] = v.y;
            Ws[(kk + 2) * 33 + jj] = v.z; Ws[(kk + 3) * 33 + jj] = v.w;
        }
        __syncthreads();
#pragma unroll
        for (int kk = 0; kk < 32; ++kk) {
            float w = Ws[kk * 33 + tx];
#pragma unroll
            for (int i = 0; i < 8; ++i) acc[i] += As[kk * 68 + ty * 8 + i] * w;
        }
        __syncthreads();
    }
    float bo = bout[j0 + tx];
#pragma unroll
    for (int i = 0; i < 8; ++i) {
        int b = ty * 8 + i;
        out[((size_t)b * T_ + t) * C_ + j0 + tx] = acc[i] + bo;
    }
}

__global__ __launch_bounds__(256) void k_final(
    const __hip_bfloat16* __restrict__ Xb, const __hip_bfloat16* __restrict__ Wb,
    const float* __restrict__ bout, float* __restrict__ out)
{
    __shared__ __hip_bfloat16 As[128 * 40];
    __shared__ __hip_bfloat16 Bs[128 * 40];
    const int tid = threadIdx.x;
    const int gr0 = blockIdx.x * 128;
    const int j0  = blockIdx.y * 128;
    const int lane = tid & 63, wave = tid >> 6;
    const int wm = (wave & 1) * 64, wn = (wave >> 1) * 64;
    const int ml = lane & 15, quad = lane >> 4;
    f32x4 acc[4][4];
#pragma unroll
    for (int a = 0; a < 4; ++a)
#pragma unroll
        for (int b = 0; b < 4; ++b) acc[a][b] = (f32x4){0.f, 0.f, 0.f, 0.f};
    for (int kc = 0; kc < 64; ++kc) {
#pragma unroll
        for (int r = 0; r < 2; ++r) {
            int s = tid + 256 * r;
            int row = s >> 2, kq = s & 3;
            *(uint4*)&As[row * 40 + kq * 8] =
                *(const uint4*)&Xb[(size_t)(gr0 + row) * 2048 + kc * 32 + kq * 8];
            *(uint4*)&Bs[row * 40 + kq * 8] =
                *(const uint4*)&Wb[(size_t)(j0 + row) * 2048 + kc * 32 + kq * 8];
        }
        __syncthreads();
        short8 af[4], bf[4];
#pragma unroll
        for (int mt = 0; mt < 4; ++mt)
            af[mt] = *(const short8*)&As[(wm + mt * 16 + ml) * 40 + quad * 8];
#pragma unroll
        for (int nt = 0; nt < 4; ++nt)
            bf[nt] = *(const short8*)&Bs[(wn + nt * 16 + ml) * 40 + quad * 8];
#pragma unroll
        for (int mt = 0; mt < 4; ++mt)
#pragma unroll
            for (int nt = 0; nt < 4; ++nt)
                acc[mt][nt] = __builtin_amdgcn_mfma_f32_16x16x32_bf16(af[mt], bf[nt], acc[mt][nt], 0, 0, 0);
        __syncthreads();
    }
#pragma unroll
    for (int nt = 0; nt < 4; ++nt) {
        int j = j0 + wn + nt * 16 + ml;
        float bo = bout[j];
#pragma unroll
        for (int mt = 0; mt < 4; ++mt) {
#pragma unroll
            for (int reg = 0; reg < 4; ++reg) {
                int r = gr0 + wm + mt * 16 + quad * 4 + reg;
                out[(size_t)r * 2048 + j] = acc[mt][nt][reg] + bo;
            }
        }
    }
}

// ---------------- host ----------------

extern "C" void kernel_launch(void* const* d_in, const int* in_sizes, int n_in,
                              void* d_out, int out_size, void* d_ws, size_t ws_size,
                              hipStream_t stream)
{
    const float* enc     = (const float*)d_in[0];
    const unsigned char* mask = (const unsigned char*)d_in[1];
    const int*   targets = (const int*)d_in[2];
    const float* E       = (const float*)d_in[3];
    const float* Wih     = (const float*)d_in[4];
    const float* Whh     = (const float*)d_in[5];
    const float* bih     = (const float*)d_in[6];
    const float* bhh     = (const float*)d_in[7];
    const float* Wout    = (const float*)d_in[8];
    const float* bout    = (const float*)d_in[9];
    float* out = (float*)d_out;

    const size_t NEED_FULL = 235000000ull;   // ~234.7 MB layout below
    const size_t NEED_MID  = 819200ull * 4 + (4194304ull + 33554432ull) * 2;  // ~78.8 MB

    if (ws_size >= NEED_FULL) {
        char* p = (char*)d_ws;
        float* h32a = (float*)p;              p += 262144;
        float* h32b = (float*)p;              p += 262144;
        unsigned short* h0h = (unsigned short*)p; p += 131072;
        unsigned short* h0l = (unsigned short*)p; p += 131072;
        float* maskf = (float*)p;             p += 65536;
        unsigned short* Wgh = (unsigned short*)p; p += 7864320;
        unsigned short* Wgl = (unsigned short*)p; p += 7864320;
        unsigned short* Xeh = (unsigned short*)p; p += 8388608;
        unsigned short* Xel = (unsigned short*)p; p += 8388608;
        unsigned short* ench = (unsigned short*)p; p += 33554432;
        unsigned short* encl = (unsigned short*)p; p += 33554432;
        unsigned short* Hh = (unsigned short*)p;  p += 33554432;
        unsigned short* Hl = (unsigned short*)p;  p += 33554432;
        float* e_all = (float*)p;             p += 16777216;
        unsigned short* Ab = (unsigned short*)p;  p += 8388608;
        unsigned short* Cb = (unsigned short*)p;  p += 33554432;
        unsigned short* Wb = (unsigned short*)p;  p += 8388608;

        k_maskprep<<<64, 256, 0, stream>>>(mask, maskf);
        k_hinit2<<<256, 256, 0, stream>>>(enc, h32a, h0h, h0l);
        k_wgprep<<<3072, 320, 0, stream>>>(Wih, Whh, Wgh, Wgl);
        k_xemb<<<dim3(256, 64), 64, 0, stream>>>(E, targets, Xeh, Xel);
        k_encprep<<<16384, 256, 0, stream>>>(enc, ench, encl);
        k_wprep<<<4096, 256, 0, stream>>>(Wout, (__hip_bfloat16*)Wb);

        for (int t = 0; t < T_; ++t) {
            const unsigned short* Xeh_t = Xeh + (size_t)t * 16384;
            const unsigned short* Xel_t = Xel + (size_t)t * 16384;
            const unsigned short* Aph = (t == 0) ? h0h : (Hh + (size_t)(t - 1) * 1024);
            const unsigned short* Apl = (t == 0) ? h0l : (Hl + (size_t)(t - 1) * 1024);
            int ap_stride = (t == 0) ? 1024 : 262144;
            const float* hp = (t & 1) ? h32b : h32a;
            float* hn = (t & 1) ? h32a : h32b;
            k_step<<<64, 256, 0, stream>>>(Xeh_t, Xel_t, Aph, Apl, ap_stride,
                                           Wgh, Wgl, bih, bhh, hp, hn,
                                           Hh + (size_t)t * 1024, Hl + (size_t)t * 1024);
        }
        k_scoresK<<<dim3(4, 64), 256, 0, stream>>>(Hh, Hl, ench, encl, e_all);
        k_softmaxK<<<4096, 256, 0, stream>>>(e_all, maskf, Ab);
        k_contextK<<<dim3(16, 64), 256, 0, stream>>>(Ab, ench, Cb);
        k_finalK<<<dim3(128, 16), 256, 0, stream>>>(Hh, Cb, Wb, bout, out);
        return;
    }

    // ---- fallback: round-2 structure ----
    float* ws    = (float*)d_ws;
    float* hbuf  = ws;
    float* gi    = ws + 131072;
    float* gh0   = gi + 196608;
    float* gh1   = gh0 + 196608;
    float* e_raw = gh1 + 196608;
    float* maskf = e_raw + 16384;
    float* cvec  = maskf + 16384;
    __hip_bfloat16* Wb = (__hip_bfloat16*)(ws + 819200);
    __hip_bfloat16* Xb = Wb + 4194304;

    const int fast = (ws_size >= NEED_MID) ? 1 : 0;

    k_maskprep<<<64, 256, 0, stream>>>(mask, maskf);
    k_hinit<<<256, 256, 0, stream>>>(enc, hbuf);
    if (fast) k_wprep<<<4096, 256, 0, stream>>>(Wout, Wb);

    for (int t = 0; t < T_; ++t) {
        float* h_cur  = hbuf + (t & 1) * 65536;
        float* h_next = hbuf + ((t + 1) & 1) * 65536;
        k_gates<<<dim3(96, 2), 256, 0, stream>>>(E, targets, Wih, Whh, bih, bhh,
                                                 h_cur, gi, gh0, gh1, t);
        k_score_h<<<dim3(4, 64), 256, 0, stream>>>(gi, gh0, gh1, h_cur, enc,
                                                   e_raw, h_next, Xb, t, fast);
        k_ctx<<<dim3(4, 64), 256, 0, stream>>>(e_raw, maskf, enc, cvec, Xb, t, fast);
        if (!fast)
            k_logits<<<64, 256, 0, stream>>>(h_next, cvec, Wout, bout, out, t);
    }
    if (fast)
        k_final<<<dim3(128, 16), 256, 0, stream>>>(Xb, Wb, bout, out);
}